// Round 4
// baseline (215.990 us; speedup 1.0000x reference)
//
#include <hip/hip_runtime.h>
#include <math.h>

constexpr int B = 4;
constexpr int N = 16384;
constexpr int D = 256;
constexpr int M = 64;
constexpr int H = 8;
// HD = 32, 3D = 768

typedef __attribute__((ext_vector_type(8))) short short8;
typedef __attribute__((ext_vector_type(4))) float floatx4;

__device__ __forceinline__ float4 ld4(const float* p) {
  return *reinterpret_cast<const float4*>(p);
}
__device__ __forceinline__ void st4(float* p, float a, float b, float c, float d) {
  *reinterpret_cast<float4*>(p) = make_float4(a, b, c, d);
}
__device__ __forceinline__ unsigned short f2bf(float f) {
  unsigned u = __float_as_uint(f);
  unsigned r = (u + 0x7fffu + ((u >> 16) & 1u)) >> 16;  // RNE
  return (unsigned short)r;
}

// XOR-swizzled LDS index (u16 elements, 16B groups, unpadded rows).
// Row stride multiple of 64 dwords => every row starts at bank 0; swizzling
// the group index by (row&7) spreads fragment reads across all banks.
__device__ __forceinline__ int swz128(int r, int c) {  // 128 u16 cols
  return r * 128 + ((((c >> 3) ^ (r & 7)) << 3) | (c & 7));
}
__device__ __forceinline__ int swz64(int r, int c) {  // 64 u16 cols
  return r * 64 + ((((c >> 3) ^ (r & 7)) << 3) | (c & 7));
}
__device__ __forceinline__ int swz256(int r, int c) {  // 256 u16 cols
  return r * 256 + ((((c >> 3) ^ (r & 7)) << 3) | (c & 7));
}

#define FMA16(acc, a4, b4)                       \
  do {                                           \
    acc[0][0] = fmaf(a4.x, b4.x, acc[0][0]);     \
    acc[0][1] = fmaf(a4.x, b4.y, acc[0][1]);     \
    acc[0][2] = fmaf(a4.x, b4.z, acc[0][2]);     \
    acc[0][3] = fmaf(a4.x, b4.w, acc[0][3]);     \
    acc[1][0] = fmaf(a4.y, b4.x, acc[1][0]);     \
    acc[1][1] = fmaf(a4.y, b4.y, acc[1][1]);     \
    acc[1][2] = fmaf(a4.y, b4.z, acc[1][2]);     \
    acc[1][3] = fmaf(a4.y, b4.w, acc[1][3]);     \
    acc[2][0] = fmaf(a4.z, b4.x, acc[2][0]);     \
    acc[2][1] = fmaf(a4.z, b4.y, acc[2][1]);     \
    acc[2][2] = fmaf(a4.z, b4.z, acc[2][2]);     \
    acc[2][3] = fmaf(a4.z, b4.w, acc[2][3]);     \
    acc[3][0] = fmaf(a4.w, b4.x, acc[3][0]);     \
    acc[3][1] = fmaf(a4.w, b4.y, acc[3][1]);     \
    acc[3][2] = fmaf(a4.w, b4.z, acc[3][2]);     \
    acc[3][3] = fmaf(a4.w, b4.w, acc[3][3]);     \
  } while (0)

// ---------------------------------------------------------------------------
// K1 (fused): reads x fp32. K-chunked (2 x 128) staging => LDS 41 KB, 3 blk/CU.
// Per 64-n tile: stage x,Ws half -> MFMA -> emit xbT half; then exp epilogue,
// En/Et emits, denom atomics.
// grid (N/64, B), block 256 (4 waves)
__global__ __launch_bounds__(256) void k1_fused(
    const float* __restrict__ x, const float* __restrict__ Ws,
    const float* __restrict__ bs, unsigned short* __restrict__ xbT,
    unsigned short* __restrict__ En, unsigned short* __restrict__ Et,
    float* __restrict__ denom) {
  __shared__ unsigned short Xt[64 * 128];  // x half-tile [n][k] swizzled
  __shared__ unsigned short Wt[64 * 128];  // Ws half-tile [m][k] swizzled
  __shared__ unsigned short Es[64 * 64];   // E tile [n][m] swizzled
  __shared__ float red[64];
  const int b = blockIdx.y;
  const int n0 = blockIdx.x * 64;
  const int tid = threadIdx.x;
  const int w = tid >> 6, l = tid & 63;
  const int q = l >> 4, q8 = q * 8;
  const int ar = w * 16 + (l & 15);

  if (tid < 64) red[tid] = 0.0f;

  floatx4 acc[4] = {{0.f, 0.f, 0.f, 0.f},
                    {0.f, 0.f, 0.f, 0.f},
                    {0.f, 0.f, 0.f, 0.f},
                    {0.f, 0.f, 0.f, 0.f}};

  for (int kc = 0; kc < 2; ++kc) {
    // stage half: 64 rows x 128 cols, fp32 -> bf16 (x and Ws)
#pragma unroll
    for (int p = 0; p < 8; ++p) {
      const int idx = p * 256 + tid;
      const int row = idx >> 5;
      const int c4 = (idx & 31) * 4;
      float4 v = ld4(&x[((size_t)(b * N + n0 + row)) * D + kc * 128 + c4]);
      unsigned u0 = (unsigned)f2bf(v.x) | ((unsigned)f2bf(v.y) << 16);
      unsigned u1 = (unsigned)f2bf(v.z) | ((unsigned)f2bf(v.w) << 16);
      *reinterpret_cast<uint2*>(&Xt[swz128(row, c4)]) = make_uint2(u0, u1);
      float4 wv = ld4(&Ws[(size_t)row * D + kc * 128 + c4]);
      unsigned w0 = (unsigned)f2bf(wv.x) | ((unsigned)f2bf(wv.y) << 16);
      unsigned w1 = (unsigned)f2bf(wv.z) | ((unsigned)f2bf(wv.w) << 16);
      *reinterpret_cast<uint2*>(&Wt[swz128(row, c4)]) = make_uint2(w0, w1);
    }
    __syncthreads();
    // MFMA over this half
#pragma unroll
    for (int ks = 0; ks < 4; ++ks) {
      short8 a = *reinterpret_cast<short8*>(&Xt[swz128(ar, ks * 32 + q8)]);
#pragma unroll
      for (int mt = 0; mt < 4; ++mt) {
        short8 bf = *reinterpret_cast<short8*>(
            &Wt[swz128(mt * 16 + (l & 15), ks * 32 + q8)]);
        acc[mt] =
            __builtin_amdgcn_mfma_f32_16x16x32_bf16(a, bf, acc[mt], 0, 0, 0);
      }
    }
    // xbT emit for this half: thread t owns d-col dc = t>>1, n-half (t&1)*32
    {
      const int dc = tid >> 1;
      const int nh = (tid & 1) * 32;
      unsigned dw[16];
#pragma unroll
      for (int j = 0; j < 16; ++j) {
        const unsigned lo = Xt[swz64(0, 0) * 0 + swz128(nh + 2 * j, dc)];
        const unsigned hi = Xt[swz128(nh + 2 * j + 1, dc)];
        dw[j] = lo | (hi << 16);
      }
      const size_t base = ((size_t)(b * D + kc * 128 + dc)) * N + n0 + nh;
      *reinterpret_cast<uint4*>(&xbT[base]) =
          make_uint4(dw[0], dw[1], dw[2], dw[3]);
      *reinterpret_cast<uint4*>(&xbT[base + 8]) =
          make_uint4(dw[4], dw[5], dw[6], dw[7]);
      *reinterpret_cast<uint4*>(&xbT[base + 16]) =
          make_uint4(dw[8], dw[9], dw[10], dw[11]);
      *reinterpret_cast<uint4*>(&xbT[base + 24]) =
          make_uint4(dw[12], dw[13], dw[14], dw[15]);
    }
    __syncthreads();
  }

  // epilogue: exp + Es + denom partials
#pragma unroll
  for (int mt = 0; mt < 4; ++mt) {
    const int m = mt * 16 + (l & 15);
    const float bsm = bs[m];
    float s = 0.0f;
#pragma unroll
    for (int r = 0; r < 4; ++r) {
      const int n = w * 16 + q * 4 + r;
      const float e = expf(acc[mt][r] + bsm);
      s += e;
      Es[swz64(n, m)] = f2bf(e);
    }
    atomicAdd(&red[m], s);
  }
  __syncthreads();
  if (tid < 64) atomicAdd(&denom[b * M + tid], red[tid]);
  // En writes (row-major, b128)
#pragma unroll
  for (int p = 0; p < 2; ++p) {
    const int g = p * 256 + tid;
    const int n = g >> 3;
    const int m0 = (g & 7) * 8;
    short8 v = *reinterpret_cast<short8*>(&Es[swz64(n, m0)]);
    *reinterpret_cast<short8*>(&En[((size_t)(b * N + n0 + n)) * M + m0]) = v;
  }
  // Et writes (transposed)
#pragma unroll
  for (int p = 0; p < 2; ++p) {
    const int g = p * 256 + tid;
    const int m = g >> 3;
    const int n8 = (g & 7) * 8;
    unsigned short bu[8];
#pragma unroll
    for (int k = 0; k < 8; ++k) bu[k] = Es[swz64(n8 + k, m)];
    uint4 pk;
    pk.x = (unsigned)bu[0] | ((unsigned)bu[1] << 16);
    pk.y = (unsigned)bu[2] | ((unsigned)bu[3] << 16);
    pk.z = (unsigned)bu[4] | ((unsigned)bu[5] << 16);
    pk.w = (unsigned)bu[6] | ((unsigned)bu[7] << 16);
    *reinterpret_cast<uint4*>(&Et[((size_t)(b * M + m)) * N + n0 + n8]) = pk;
  }
}

// ---------------------------------------------------------------------------
// K2: tokens_raw[b,m,d] += sum_n Et[b,m,n] * xbT[b,d,n]   (split-K over N)
// grid (D/64, N/512, B), block 256
__global__ __launch_bounds__(256) void k2_pool(
    const unsigned short* __restrict__ Et, const unsigned short* __restrict__ xbT,
    float* __restrict__ tokens) {
  __shared__ unsigned short EtS[64 * 64];
  __shared__ unsigned short XtS[64 * 64];
  const int dt = blockIdx.x, nc = blockIdx.y, b = blockIdx.z;
  const int d0 = dt * 64;
  const int tid = threadIdx.x;
  const int w = tid >> 6, l = tid & 63;
  floatx4 acc[4] = {{0.f, 0.f, 0.f, 0.f},
                    {0.f, 0.f, 0.f, 0.f},
                    {0.f, 0.f, 0.f, 0.f},
                    {0.f, 0.f, 0.f, 0.f}};
  const int q8 = (l >> 4) * 8;
  for (int kc = 0; kc < 8; ++kc) {
    const int nb = nc * 512 + kc * 64;
    __syncthreads();
#pragma unroll
    for (int p = 0; p < 2; ++p) {
      const int g = p * 256 + tid;
      const int row = g >> 3;
      const int c8 = (g & 7) * 8;
      *reinterpret_cast<short8*>(&EtS[swz64(row, c8)]) =
          *reinterpret_cast<const short8*>(
              &Et[((size_t)(b * M + row)) * N + nb + c8]);
      *reinterpret_cast<short8*>(&XtS[swz64(row, c8)]) =
          *reinterpret_cast<const short8*>(
              &xbT[((size_t)(b * D + d0 + row)) * N + nb + c8]);
    }
    __syncthreads();
#pragma unroll
    for (int ks = 0; ks < 2; ++ks) {
      short8 a = *reinterpret_cast<short8*>(
          &EtS[swz64(w * 16 + (l & 15), ks * 32 + q8)]);
#pragma unroll
      for (int dtile = 0; dtile < 4; ++dtile) {
        short8 bf = *reinterpret_cast<short8*>(
            &XtS[swz64(dtile * 16 + (l & 15), ks * 32 + q8)]);
        acc[dtile] =
            __builtin_amdgcn_mfma_f32_16x16x32_bf16(a, bf, acc[dtile], 0, 0, 0);
      }
    }
  }
#pragma unroll
  for (int dtile = 0; dtile < 4; ++dtile)
#pragma unroll
    for (int r = 0; r < 4; ++r) {
      const int m = w * 16 + (l >> 4) * 4 + r;
      const int d = d0 + dtile * 16 + (l & 15);
      atomicAdd(&tokens[((size_t)(b * M + m)) * D + d], acc[dtile][r]);
    }
}

// ---------------------------------------------------------------------------
// K3/K5 (MFMA): Out[b,m,e] = (A[b,m,:] . W[e,:] + bias[e]) / denom[b,m]
// grid (EC/64, B), block 256
__global__ __launch_bounds__(256) void k_proj(
    const float* __restrict__ A, const float* __restrict__ W,
    const float* __restrict__ bias, const float* __restrict__ denom,
    float* __restrict__ OutF, unsigned short* __restrict__ OutT, const int EC,
    const int mode) {
  __shared__ unsigned short At[64 * 256];
  __shared__ unsigned short Wt[64 * 256];
  __shared__ float Cs[64][68];
  const int et = blockIdx.x;
  const int b = blockIdx.y;
  const int tid = threadIdx.x;
  const int w = tid >> 6, l = tid & 63;
  const int q8 = (l >> 4) * 8;
#pragma unroll
  for (int p = 0; p < 16; ++p) {
    const int i = p * 256 + tid;
    const int row = i >> 6;
    const int c4 = (i & 63) * 4;
    float4 av = ld4(&A[((size_t)(b * M + row)) * D + c4]);
    unsigned a0 = (unsigned)f2bf(av.x) | ((unsigned)f2bf(av.y) << 16);
    unsigned a1 = (unsigned)f2bf(av.z) | ((unsigned)f2bf(av.w) << 16);
    *reinterpret_cast<uint2*>(&At[swz256(row, c4)]) = make_uint2(a0, a1);
    float4 wv = ld4(&W[((size_t)(et * 64 + row)) * D + c4]);
    unsigned w0 = (unsigned)f2bf(wv.x) | ((unsigned)f2bf(wv.y) << 16);
    unsigned w1 = (unsigned)f2bf(wv.z) | ((unsigned)f2bf(wv.w) << 16);
    *reinterpret_cast<uint2*>(&Wt[swz256(row, c4)]) = make_uint2(w0, w1);
  }
  __syncthreads();
  floatx4 acc[4] = {{0.f, 0.f, 0.f, 0.f},
                    {0.f, 0.f, 0.f, 0.f},
                    {0.f, 0.f, 0.f, 0.f},
                    {0.f, 0.f, 0.f, 0.f}};
  const int ar = w * 16 + (l & 15);
#pragma unroll
  for (int ks = 0; ks < 8; ++ks) {
    short8 a = *reinterpret_cast<short8*>(&At[swz256(ar, ks * 32 + q8)]);
#pragma unroll
    for (int mt = 0; mt < 4; ++mt) {
      short8 bf = *reinterpret_cast<short8*>(
          &Wt[swz256(mt * 16 + (l & 15), ks * 32 + q8)]);
      acc[mt] = __builtin_amdgcn_mfma_f32_16x16x32_bf16(a, bf, acc[mt], 0, 0, 0);
    }
  }
  if (mode == 0) {
#pragma unroll
    for (int mt = 0; mt < 4; ++mt) {
#pragma unroll
      for (int r = 0; r < 4; ++r) {
        const int row = w * 16 + (l >> 4) * 4 + r;  // m
        const float rcp = 1.0f / denom[b * M + row];
        const int e = et * 64 + mt * 16 + (l & 15);
        OutF[((size_t)(b * M + row)) * EC + e] = acc[mt][r] * rcp;
      }
    }
  } else {
#pragma unroll
    for (int mt = 0; mt < 4; ++mt) {
#pragma unroll
      for (int r = 0; r < 4; ++r) {
        const int row = w * 16 + (l >> 4) * 4 + r;  // m
        const float rcp = 1.0f / denom[b * M + row];
        const int el = mt * 16 + (l & 15);
        const float bv = bias[et * 64 + el];
        Cs[row][el] = (acc[mt][r] + bv) * rcp;
      }
    }
    __syncthreads();
    // transposed bf16 write: OutT[b, e, m]
#pragma unroll
    for (int p = 0; p < 2; ++p) {
      const int g = p * 256 + tid;
      const int e = g >> 3;       // 0..63
      const int m0 = (g & 7) * 8;
      unsigned short bu[8];
#pragma unroll
      for (int k = 0; k < 8; ++k) bu[k] = f2bf(Cs[m0 + k][e]);
      uint4 pk;
      pk.x = (unsigned)bu[0] | ((unsigned)bu[1] << 16);
      pk.y = (unsigned)bu[2] | ((unsigned)bu[3] << 16);
      pk.z = (unsigned)bu[4] | ((unsigned)bu[5] << 16);
      pk.w = (unsigned)bu[6] | ((unsigned)bu[7] << 16);
      *reinterpret_cast<uint4*>(
          &OutT[((size_t)(b * D + et * 64 + e)) * M + m0]) = pk;
    }
  }
}

// ---------------------------------------------------------------------------
// K4: per (b,h) attention over M=64 tokens, HD=32 (fp32)
// grid (B*H), block 256
__global__ __launch_bounds__(256) void k4_attn(
    const float* __restrict__ qkv, float* __restrict__ attn_o) {
  __shared__ float qt[32][68];
  __shared__ float kt[32][68];
  __shared__ float vv[64][36];
  __shared__ float P[64][68];
  const int b = blockIdx.x >> 3;
  const int h = blockIdx.x & 7;
  const int tid = threadIdx.x;
  for (int i = tid; i < 512; i += 256) {
    const int m = i >> 3;
    const int c4 = (i & 7) * 4;
    const float* base = &qkv[((size_t)(b * M + m)) * 768 + h * 32 + c4];
    float4 q4 = ld4(base);
    float4 k4 = ld4(base + 256);
    float4 v4 = ld4(base + 512);
    qt[c4 + 0][m] = q4.x; qt[c4 + 1][m] = q4.y; qt[c4 + 2][m] = q4.z; qt[c4 + 3][m] = q4.w;
    kt[c4 + 0][m] = k4.x; kt[c4 + 1][m] = k4.y; kt[c4 + 2][m] = k4.z; kt[c4 + 3][m] = k4.w;
    *reinterpret_cast<float4*>(&vv[m][c4]) = v4;
  }
  __syncthreads();
  {
    const int tm4 = (tid & 15) * 4;
    const int tn4 = (tid >> 4) * 4;
    float acc[4][4] = {};
    for (int k = 0; k < 32; ++k) {
      float4 a4 = ld4(&qt[k][tn4]);
      float4 b4 = ld4(&kt[k][tm4]);
      FMA16(acc, a4, b4);
    }
    const float scale = 0.17677669529663687f;
#pragma unroll
    for (int i = 0; i < 4; ++i)
      st4(&P[tn4 + i][tm4], acc[i][0] * scale, acc[i][1] * scale,
          acc[i][2] * scale, acc[i][3] * scale);
  }
  __syncthreads();
  if (tid < 64) {
    float mx = -1e30f;
    for (int j = 0; j < 64; ++j) mx = fmaxf(mx, P[tid][j]);
    float s = 0.0f;
    for (int j = 0; j < 64; ++j) {
      const float e = expf(P[tid][j] - mx);
      P[tid][j] = e;
      s += e;
    }
    const float r = 1.0f / s;
    for (int j = 0; j < 64; ++j) P[tid][j] *= r;
  }
  __syncthreads();
  if (tid < 128) {
    const int i0 = (tid >> 3) * 4;
    const int c0 = (tid & 7) * 4;
    float o[4][4] = {};
    for (int j = 0; j < 64; ++j) {
      float4 v4 = ld4(&vv[j][c0]);
#pragma unroll
      for (int ii = 0; ii < 4; ++ii) {
        const float p = P[i0 + ii][j];
        o[ii][0] = fmaf(p, v4.x, o[ii][0]);
        o[ii][1] = fmaf(p, v4.y, o[ii][1]);
        o[ii][2] = fmaf(p, v4.z, o[ii][2]);
        o[ii][3] = fmaf(p, v4.w, o[ii][3]);
      }
    }
#pragma unroll
    for (int ii = 0; ii < 4; ++ii)
      st4(&attn_o[((size_t)(b * M + i0 + ii)) * D + h * 32 + c0],
          o[ii][0], o[ii][1], o[ii][2], o[ii][3]);
  }
}

// ---------------------------------------------------------------------------
// K6: out[b,n,d] = sum_m En[b,n,m] * TpT[b,d,m]   (MFMA, K=64)
// grid (D/64, N/64, B), block 256
__global__ __launch_bounds__(256) void k6_unpool(
    const unsigned short* __restrict__ En, const unsigned short* __restrict__ TpT,
    float* __restrict__ out) {
  __shared__ unsigned short EnS[64 * 64];
  __shared__ unsigned short TpS[64 * 64];
  const int dt = blockIdx.x, nt = blockIdx.y, b = blockIdx.z;
  const int n0 = nt * 64, d0 = dt * 64;
  const int tid = threadIdx.x;
  const int w = tid >> 6, l = tid & 63;
#pragma unroll
  for (int p = 0; p < 2; ++p) {
    const int g = p * 256 + tid;
    const int row = g >> 3;
    const int c8 = (g & 7) * 8;
    *reinterpret_cast<short8*>(&EnS[swz64(row, c8)]) =
        *reinterpret_cast<const short8*>(
            &En[((size_t)(b * N + n0 + row)) * M + c8]);
    *reinterpret_cast<short8*>(&TpS[swz64(row, c8)]) =
        *reinterpret_cast<const short8*>(
            &TpT[((size_t)(b * D + d0 + row)) * M + c8]);
  }
  __syncthreads();
  floatx4 acc[4] = {{0.f, 0.f, 0.f, 0.f},
                    {0.f, 0.f, 0.f, 0.f},
                    {0.f, 0.f, 0.f, 0.f},
                    {0.f, 0.f, 0.f, 0.f}};
  const int q8 = (l >> 4) * 8;
#pragma unroll
  for (int ks = 0; ks < 2; ++ks) {
    short8 a = *reinterpret_cast<short8*>(
        &EnS[swz64(w * 16 + (l & 15), ks * 32 + q8)]);
#pragma unroll
    for (int dtile = 0; dtile < 4; ++dtile) {
      short8 bf = *reinterpret_cast<short8*>(
          &TpS[swz64(dtile * 16 + (l & 15), ks * 32 + q8)]);
      acc[dtile] =
          __builtin_amdgcn_mfma_f32_16x16x32_bf16(a, bf, acc[dtile], 0, 0, 0);
    }
  }
#pragma unroll
  for (int dtile = 0; dtile < 4; ++dtile)
#pragma unroll
    for (int r = 0; r < 4; ++r) {
      const int n = n0 + w * 16 + (l >> 4) * 4 + r;
      const int d = d0 + dtile * 16 + (l & 15);
      out[((size_t)(b * N + n)) * D + d] = acc[dtile][r];
    }
}

// ---------------------------------------------------------------------------
extern "C" void kernel_launch(void* const* d_in, const int* in_sizes, int n_in,
                              void* d_out, int out_size, void* d_ws,
                              size_t ws_size, hipStream_t stream) {
  const float* x = (const float*)d_in[0];
  const float* Ws = (const float*)d_in[1];
  const float* bs = (const float*)d_in[2];
  const float* Wqkv = (const float*)d_in[3];
  const float* Wo = (const float*)d_in[4];
  const float* bo = (const float*)d_in[5];
  float* out = (float*)d_out;

  char* p = (char*)d_ws;
  unsigned short* xbT = (unsigned short*)p;      p += (size_t)B * N * D * 2;   // 33.5 MB
  unsigned short* En = (unsigned short*)p;       p += (size_t)B * N * M * 2;   // 8.4 MB
  unsigned short* Et = (unsigned short*)p;       p += (size_t)B * N * M * 2;   // 8.4 MB
  unsigned short* TpT = (unsigned short*)p;      p += (size_t)B * D * M * 2;   // 128 KB
  float* denom = (float*)p;                      p += (size_t)B * M * 4;
  float* tokens = (float*)p;                     p += (size_t)B * M * D * 4;
  float* qkv = (float*)p;                        p += (size_t)B * M * 3 * D * 4;
  float* attn_o = (float*)p;                     p += (size_t)B * M * D * 4;

  hipMemsetAsync(denom, 0, (size_t)B * M * sizeof(float), stream);
  hipMemsetAsync(tokens, 0, (size_t)B * M * D * sizeof(float), stream);

  k1_fused<<<dim3(N / 64, B), 256, 0, stream>>>(x, Ws, bs, xbT, En, Et, denom);
  k2_pool<<<dim3(D / 64, N / 512, B), 256, 0, stream>>>(Et, xbT, tokens);
  k_proj<<<dim3(12, B), 256, 0, stream>>>(tokens, Wqkv, nullptr, denom, qkv,
                                          nullptr, 768, 0);
  k4_attn<<<dim3(B * H), 256, 0, stream>>>(qkv, attn_o);
  k_proj<<<dim3(4, B), 256, 0, stream>>>(attn_o, Wo, bo, denom, nullptr, TpT,
                                         256, 1);
  k6_unpool<<<dim3(D / 64, N / 64, B), 256, 0, stream>>>(En, TpT, out);
}

// Round 5
// 207.349 us; speedup vs baseline: 1.0417x; 1.0417x over previous
//
#include <hip/hip_runtime.h>
#include <math.h>

constexpr int B = 4;
constexpr int N = 16384;
constexpr int D = 256;
constexpr int M = 64;
constexpr int H = 8;
// HD = 32, 3D = 768

typedef __attribute__((ext_vector_type(8))) short short8;
typedef __attribute__((ext_vector_type(4))) float floatx4;

__device__ __forceinline__ float4 ld4(const float* p) {
  return *reinterpret_cast<const float4*>(p);
}
__device__ __forceinline__ void st4(float* p, float a, float b, float c, float d) {
  *reinterpret_cast<float4*>(p) = make_float4(a, b, c, d);
}
__device__ __forceinline__ unsigned short f2bf(float f) {
  unsigned u = __float_as_uint(f);
  unsigned r = (u + 0x7fffu + ((u >> 16) & 1u)) >> 16;  // RNE
  return (unsigned short)r;
}

// XOR swizzle on 16B groups for a 256-u16-wide row (row stride 128 dwords,
// bank-aligned): spreads b128 fragment reads across all 32 banks; column
// (transpose) reads remain conflict-free.
__device__ __forceinline__ int swz256(int r, int c) {
  return r * 256 + ((((c >> 3) ^ (r & 7)) << 3) | (c & 7));
}

#define FMA16(acc, a4, b4)                       \
  do {                                           \
    acc[0][0] = fmaf(a4.x, b4.x, acc[0][0]);     \
    acc[0][1] = fmaf(a4.x, b4.y, acc[0][1]);     \
    acc[0][2] = fmaf(a4.x, b4.z, acc[0][2]);     \
    acc[0][3] = fmaf(a4.x, b4.w, acc[0][3]);     \
    acc[1][0] = fmaf(a4.y, b4.x, acc[1][0]);     \
    acc[1][1] = fmaf(a4.y, b4.y, acc[1][1]);     \
    acc[1][2] = fmaf(a4.y, b4.z, acc[1][2]);     \
    acc[1][3] = fmaf(a4.y, b4.w, acc[1][3]);     \
    acc[2][0] = fmaf(a4.z, b4.x, acc[2][0]);     \
    acc[2][1] = fmaf(a4.z, b4.y, acc[2][1]);     \
    acc[2][2] = fmaf(a4.z, b4.z, acc[2][2]);     \
    acc[2][3] = fmaf(a4.z, b4.w, acc[2][3]);     \
    acc[3][0] = fmaf(a4.w, b4.x, acc[3][0]);     \
    acc[3][1] = fmaf(a4.w, b4.y, acc[3][1]);     \
    acc[3][2] = fmaf(a4.w, b4.z, acc[3][2]);     \
    acc[3][3] = fmaf(a4.w, b4.w, acc[3][3]);     \
  } while (0)

// ---------------------------------------------------------------------------
// KW: Ws (fp32, 64x256) -> Wsb (bf16). grid(16), block 256.
__global__ __launch_bounds__(256) void kws_cvt(const float* __restrict__ Ws,
                                               unsigned short* __restrict__ Wsb) {
  const int i = blockIdx.x * 256 + threadIdx.x;  // 4096 float4
  float4 v = ld4(&Ws[(size_t)i * 4]);
  unsigned u0 = (unsigned)f2bf(v.x) | ((unsigned)f2bf(v.y) << 16);
  unsigned u1 = (unsigned)f2bf(v.z) | ((unsigned)f2bf(v.w) << 16);
  *reinterpret_cast<uint2*>(&Wsb[(size_t)i * 4]) = make_uint2(u0, u1);
}

// ---------------------------------------------------------------------------
// K1: per 32-n tile (2048 blocks): stage x->bf16 LDS (swizzled), MFMA logits
// with B-fragments straight from global Wsb (L1/L2-resident), exp epilogue,
// emit xbT (tiled [b][n/64][d][64]), En ([b][n][m]), Et (tiled [b][n/64][m][64]),
// denom atomics. LDS ~20.3 KB -> ~7 blocks/CU.
// grid (N/32, B), block 256 (4 waves)
__global__ __launch_bounds__(256) void k1_fused(
    const float* __restrict__ x, const unsigned short* __restrict__ Wsb,
    const float* __restrict__ bs, unsigned short* __restrict__ xbT,
    unsigned short* __restrict__ En, unsigned short* __restrict__ Et,
    float* __restrict__ denom) {
  __shared__ unsigned short Xt[32 * 256];  // x tile [n][d] bf16, swizzled
  __shared__ unsigned short Es[32 * 64];   // E tile [n][m] bf16, row-major
  __shared__ float red[64];
  const int b = blockIdx.y;
  const int n0 = blockIdx.x * 32;
  const int tile = n0 >> 6;   // 64-n tile index
  const int half = n0 & 32;   // which half of the 64-tile
  const int tid = threadIdx.x;
  const int w = tid >> 6, l = tid & 63;
  const int q = l >> 4, q8 = q * 8;
  const int wn = (w & 1) * 16;      // n-sub of this wave
  const int mt0 = (w >> 1) * 2;     // m-tile base of this wave

  if (tid < 64) red[tid] = 0.0f;

  // stage x: 32 rows x 256 cols fp32 -> bf16 swizzled
#pragma unroll
  for (int p = 0; p < 8; ++p) {
    const int idx = p * 256 + tid;
    const int row = idx >> 6;
    const int c4 = (idx & 63) * 4;
    float4 v = ld4(&x[((size_t)(b * N + n0 + row)) * D + c4]);
    unsigned u0 = (unsigned)f2bf(v.x) | ((unsigned)f2bf(v.y) << 16);
    unsigned u1 = (unsigned)f2bf(v.z) | ((unsigned)f2bf(v.w) << 16);
    *reinterpret_cast<uint2*>(&Xt[swz256(row, c4)]) = make_uint2(u0, u1);
  }
  __syncthreads();

  // MFMA: C[n,m] = sum_d x[n,d]*Ws[m,d]; B-fragments from global Wsb
  floatx4 acc0 = {0.f, 0.f, 0.f, 0.f};
  floatx4 acc1 = {0.f, 0.f, 0.f, 0.f};
  const int ar = wn + (l & 15);
  const int br0 = (mt0 * 16 + (l & 15)) * 256;
  const int br1 = ((mt0 + 1) * 16 + (l & 15)) * 256;
#pragma unroll
  for (int ks = 0; ks < 8; ++ks) {
    short8 a = *reinterpret_cast<short8*>(&Xt[swz256(ar, ks * 32 + q8)]);
    short8 b0 = *reinterpret_cast<const short8*>(&Wsb[br0 + ks * 32 + q8]);
    short8 b1 = *reinterpret_cast<const short8*>(&Wsb[br1 + ks * 32 + q8]);
    acc0 = __builtin_amdgcn_mfma_f32_16x16x32_bf16(a, b0, acc0, 0, 0, 0);
    acc1 = __builtin_amdgcn_mfma_f32_16x16x32_bf16(a, b1, acc1, 0, 0, 0);
  }

  // xbT emit: tiled layout [b][n/64][d][64]; thread tid owns d-col tid
  {
    unsigned dw[16];
#pragma unroll
    for (int j = 0; j < 16; ++j) {
      const unsigned lo = Xt[swz256(2 * j, tid)];
      const unsigned hi = Xt[swz256(2 * j + 1, tid)];
      dw[j] = lo | (hi << 16);
    }
    const size_t base = (((size_t)(b * (N / 64) + tile)) * D + tid) * 64 + half;
    *reinterpret_cast<uint4*>(&xbT[base]) = make_uint4(dw[0], dw[1], dw[2], dw[3]);
    *reinterpret_cast<uint4*>(&xbT[base + 8]) = make_uint4(dw[4], dw[5], dw[6], dw[7]);
    *reinterpret_cast<uint4*>(&xbT[base + 16]) = make_uint4(dw[8], dw[9], dw[10], dw[11]);
    *reinterpret_cast<uint4*>(&xbT[base + 24]) = make_uint4(dw[12], dw[13], dw[14], dw[15]);
  }

  // exp epilogue -> Es + denom partials
  {
    const float bs0 = bs[mt0 * 16 + (l & 15)];
    const float bs1 = bs[(mt0 + 1) * 16 + (l & 15)];
    float s0 = 0.f, s1 = 0.f;
#pragma unroll
    for (int r = 0; r < 4; ++r) {
      const int n = wn + q * 4 + r;
      const float e0 = expf(acc0[r] + bs0);
      const float e1 = expf(acc1[r] + bs1);
      s0 += e0;
      s1 += e1;
      Es[n * 64 + mt0 * 16 + (l & 15)] = f2bf(e0);
      Es[n * 64 + (mt0 + 1) * 16 + (l & 15)] = f2bf(e1);
    }
    atomicAdd(&red[mt0 * 16 + (l & 15)], s0);
    atomicAdd(&red[(mt0 + 1) * 16 + (l & 15)], s1);
  }
  __syncthreads();
  if (tid < 64) atomicAdd(&denom[b * M + tid], red[tid]);

  // En emit: [b][n][m] row-major; Es linear b128, conflict-free, coalesced
  {
    short8 v = *reinterpret_cast<short8*>(&Es[tid * 8]);
    const int n = tid >> 3, m0 = (tid & 7) * 8;
    *reinterpret_cast<short8*>(&En[((size_t)(b * N + n0 + n)) * M + m0]) = v;
  }
  // Et emit: tiled [b][n/64][m][64]
  {
    const int m = tid >> 2;
    const int n8 = (tid & 3) * 8;
    unsigned short bu[8];
#pragma unroll
    for (int k = 0; k < 8; ++k) bu[k] = Es[(n8 + k) * 64 + m];
    uint4 pk;
    pk.x = (unsigned)bu[0] | ((unsigned)bu[1] << 16);
    pk.y = (unsigned)bu[2] | ((unsigned)bu[3] << 16);
    pk.z = (unsigned)bu[4] | ((unsigned)bu[5] << 16);
    pk.w = (unsigned)bu[6] | ((unsigned)bu[7] << 16);
    const size_t base =
        (((size_t)(b * (N / 64) + tile)) * M + m) * 64 + half + n8;
    *reinterpret_cast<uint4*>(&Et[base]) = pk;
  }
}

// ---------------------------------------------------------------------------
// K2: tokens_raw[b,m,d] += sum_n Et[b,nt,m,:] * xbT[b,nt,d,:] (split-K over N)
// Tiled inputs: fully contiguous 8KB loads per 64-n tile.
// grid (D/64, N/512, B), block 256
__global__ __launch_bounds__(256) void k2_pool(
    const unsigned short* __restrict__ Et, const unsigned short* __restrict__ xbT,
    float* __restrict__ tokens) {
  __shared__ unsigned short EtS[64][72];
  __shared__ unsigned short XtS[64][72];
  const int dt = blockIdx.x, nc = blockIdx.y, b = blockIdx.z;
  const int d0 = dt * 64;
  const int tid = threadIdx.x;
  const int w = tid >> 6, l = tid & 63;
  floatx4 acc[4] = {{0.f, 0.f, 0.f, 0.f},
                    {0.f, 0.f, 0.f, 0.f},
                    {0.f, 0.f, 0.f, 0.f},
                    {0.f, 0.f, 0.f, 0.f}};
  const int q8 = (l >> 4) * 8;
  for (int kc = 0; kc < 8; ++kc) {
    const int tIdx = nc * 8 + kc;  // 64-n tile index
    __syncthreads();
#pragma unroll
    for (int p = 0; p < 2; ++p) {
      const int g = p * 256 + tid;
      const int row = g >> 3;
      const int c8 = (g & 7) * 8;
      *reinterpret_cast<short8*>(&EtS[row][c8]) =
          *reinterpret_cast<const short8*>(
              &Et[(((size_t)(b * (N / 64) + tIdx)) * M + row) * 64 + c8]);
      *reinterpret_cast<short8*>(&XtS[row][c8]) =
          *reinterpret_cast<const short8*>(
              &xbT[(((size_t)(b * (N / 64) + tIdx)) * D + d0 + row) * 64 + c8]);
    }
    __syncthreads();
#pragma unroll
    for (int ks = 0; ks < 2; ++ks) {
      short8 a = *reinterpret_cast<short8*>(&EtS[w * 16 + (l & 15)][ks * 32 + q8]);
#pragma unroll
      for (int dtile = 0; dtile < 4; ++dtile) {
        short8 bf = *reinterpret_cast<short8*>(
            &XtS[dtile * 16 + (l & 15)][ks * 32 + q8]);
        acc[dtile] =
            __builtin_amdgcn_mfma_f32_16x16x32_bf16(a, bf, acc[dtile], 0, 0, 0);
      }
    }
  }
#pragma unroll
  for (int dtile = 0; dtile < 4; ++dtile)
#pragma unroll
    for (int r = 0; r < 4; ++r) {
      const int m = w * 16 + (l >> 4) * 4 + r;
      const int d = d0 + dtile * 16 + (l & 15);
      atomicAdd(&tokens[((size_t)(b * M + m)) * D + d], acc[dtile][r]);
    }
}

// ---------------------------------------------------------------------------
// K3/K5 (MFMA): Out[b,m,e] = (A[b,m,:] . W[e,:] + bias[e]) / denom[b,m]
// grid (EC/64, B), block 256
__global__ __launch_bounds__(256) void k_proj(
    const float* __restrict__ A, const float* __restrict__ W,
    const float* __restrict__ bias, const float* __restrict__ denom,
    float* __restrict__ OutF, unsigned short* __restrict__ OutT, const int EC,
    const int mode) {
  __shared__ unsigned short At[64][264];
  __shared__ unsigned short Wt[64][264];
  __shared__ float Cs[64][68];
  const int et = blockIdx.x;
  const int b = blockIdx.y;
  const int tid = threadIdx.x;
  const int w = tid >> 6, l = tid & 63;
  const int q8 = (l >> 4) * 8;
#pragma unroll
  for (int p = 0; p < 16; ++p) {
    const int i = p * 256 + tid;
    const int row = i >> 6;
    const int c4 = (i & 63) * 4;
    float4 av = ld4(&A[((size_t)(b * M + row)) * D + c4]);
    unsigned a0 = (unsigned)f2bf(av.x) | ((unsigned)f2bf(av.y) << 16);
    unsigned a1 = (unsigned)f2bf(av.z) | ((unsigned)f2bf(av.w) << 16);
    *reinterpret_cast<uint2*>(&At[row][c4]) = make_uint2(a0, a1);
    float4 wv = ld4(&W[((size_t)(et * 64 + row)) * D + c4]);
    unsigned w0 = (unsigned)f2bf(wv.x) | ((unsigned)f2bf(wv.y) << 16);
    unsigned w1 = (unsigned)f2bf(wv.z) | ((unsigned)f2bf(wv.w) << 16);
    *reinterpret_cast<uint2*>(&Wt[row][c4]) = make_uint2(w0, w1);
  }
  __syncthreads();
  floatx4 acc[4] = {{0.f, 0.f, 0.f, 0.f},
                    {0.f, 0.f, 0.f, 0.f},
                    {0.f, 0.f, 0.f, 0.f},
                    {0.f, 0.f, 0.f, 0.f}};
  const int ar = w * 16 + (l & 15);
#pragma unroll
  for (int ks = 0; ks < 8; ++ks) {
    short8 a = *reinterpret_cast<short8*>(&At[ar][ks * 32 + q8]);
#pragma unroll
    for (int mt = 0; mt < 4; ++mt) {
      short8 bf = *reinterpret_cast<short8*>(&Wt[mt * 16 + (l & 15)][ks * 32 + q8]);
      acc[mt] = __builtin_amdgcn_mfma_f32_16x16x32_bf16(a, bf, acc[mt], 0, 0, 0);
    }
  }
  if (mode == 0) {
#pragma unroll
    for (int mt = 0; mt < 4; ++mt) {
#pragma unroll
      for (int r = 0; r < 4; ++r) {
        const int row = w * 16 + (l >> 4) * 4 + r;  // m
        const float rcp = 1.0f / denom[b * M + row];
        const int e = et * 64 + mt * 16 + (l & 15);
        OutF[((size_t)(b * M + row)) * EC + e] = acc[mt][r] * rcp;
      }
    }
  } else {
#pragma unroll
    for (int mt = 0; mt < 4; ++mt) {
#pragma unroll
      for (int r = 0; r < 4; ++r) {
        const int row = w * 16 + (l >> 4) * 4 + r;  // m
        const float rcp = 1.0f / denom[b * M + row];
        const int el = mt * 16 + (l & 15);
        const float bv = bias[et * 64 + el];
        Cs[row][el] = (acc[mt][r] + bv) * rcp;
      }
    }
    __syncthreads();
    // transposed bf16 write: OutT[b, e, m]
#pragma unroll
    for (int p = 0; p < 2; ++p) {
      const int g = p * 256 + tid;
      const int e = g >> 3;       // 0..63
      const int m0 = (g & 7) * 8;
      unsigned short bu[8];
#pragma unroll
      for (int k = 0; k < 8; ++k) bu[k] = f2bf(Cs[m0 + k][e]);
      uint4 pk;
      pk.x = (unsigned)bu[0] | ((unsigned)bu[1] << 16);
      pk.y = (unsigned)bu[2] | ((unsigned)bu[3] << 16);
      pk.z = (unsigned)bu[4] | ((unsigned)bu[5] << 16);
      pk.w = (unsigned)bu[6] | ((unsigned)bu[7] << 16);
      *reinterpret_cast<uint4*>(
          &OutT[((size_t)(b * D + et * 64 + e)) * M + m0]) = pk;
    }
  }
}

// ---------------------------------------------------------------------------
// K4: per (b,h) attention over M=64 tokens, HD=32 (fp32)
// grid (B*H), block 256
__global__ __launch_bounds__(256) void k4_attn(
    const float* __restrict__ qkv, float* __restrict__ attn_o) {
  __shared__ float qt[32][68];
  __shared__ float kt[32][68];
  __shared__ float vv[64][36];
  __shared__ float P[64][68];
  const int b = blockIdx.x >> 3;
  const int h = blockIdx.x & 7;
  const int tid = threadIdx.x;
  for (int i = tid; i < 512; i += 256) {
    const int m = i >> 3;
    const int c4 = (i & 7) * 4;
    const float* base = &qkv[((size_t)(b * M + m)) * 768 + h * 32 + c4];
    float4 q4 = ld4(base);
    float4 k4 = ld4(base + 256);
    float4 v4 = ld4(base + 512);
    qt[c4 + 0][m] = q4.x; qt[c4 + 1][m] = q4.y; qt[c4 + 2][m] = q4.z; qt[c4 + 3][m] = q4.w;
    kt[c4 + 0][m] = k4.x; kt[c4 + 1][m] = k4.y; kt[c4 + 2][m] = k4.z; kt[c4 + 3][m] = k4.w;
    *reinterpret_cast<float4*>(&vv[m][c4]) = v4;
  }
  __syncthreads();
  {
    const int tm4 = (tid & 15) * 4;
    const int tn4 = (tid >> 4) * 4;
    float acc[4][4] = {};
    for (int k = 0; k < 32; ++k) {
      float4 a4 = ld4(&qt[k][tn4]);
      float4 b4 = ld4(&kt[k][tm4]);
      FMA16(acc, a4, b4);
    }
    const float scale = 0.17677669529663687f;
#pragma unroll
    for (int i = 0; i < 4; ++i)
      st4(&P[tn4 + i][tm4], acc[i][0] * scale, acc[i][1] * scale,
          acc[i][2] * scale, acc[i][3] * scale);
  }
  __syncthreads();
  if (tid < 64) {
    float mx = -1e30f;
    for (int j = 0; j < 64; ++j) mx = fmaxf(mx, P[tid][j]);
    float s = 0.0f;
    for (int j = 0; j < 64; ++j) {
      const float e = expf(P[tid][j] - mx);
      P[tid][j] = e;
      s += e;
    }
    const float r = 1.0f / s;
    for (int j = 0; j < 64; ++j) P[tid][j] *= r;
  }
  __syncthreads();
  if (tid < 128) {
    const int i0 = (tid >> 3) * 4;
    const int c0 = (tid & 7) * 4;
    float o[4][4] = {};
    for (int j = 0; j < 64; ++j) {
      float4 v4 = ld4(&vv[j][c0]);
#pragma unroll
      for (int ii = 0; ii < 4; ++ii) {
        const float p = P[i0 + ii][j];
        o[ii][0] = fmaf(p, v4.x, o[ii][0]);
        o[ii][1] = fmaf(p, v4.y, o[ii][1]);
        o[ii][2] = fmaf(p, v4.z, o[ii][2]);
        o[ii][3] = fmaf(p, v4.w, o[ii][3]);
      }
    }
#pragma unroll
    for (int ii = 0; ii < 4; ++ii)
      st4(&attn_o[((size_t)(b * M + i0 + ii)) * D + h * 32 + c0],
          o[ii][0], o[ii][1], o[ii][2], o[ii][3]);
  }
}

// ---------------------------------------------------------------------------
// K6: out[b,n,d] = sum_m En[b,n,m] * TpT[b,d,m]   (MFMA, K=64)
// grid (D/64, N/64, B), block 256
__global__ __launch_bounds__(256) void k6_unpool(
    const unsigned short* __restrict__ En, const unsigned short* __restrict__ TpT,
    float* __restrict__ out) {
  __shared__ unsigned short EnS[64][72];
  __shared__ unsigned short TpS[64][72];
  const int dt = blockIdx.x, nt = blockIdx.y, b = blockIdx.z;
  const int n0 = nt * 64, d0 = dt * 64;
  const int tid = threadIdx.x;
  const int w = tid >> 6, l = tid & 63;
#pragma unroll
  for (int p = 0; p < 2; ++p) {
    const int g = p * 256 + tid;
    const int row = g >> 3;
    const int c8 = (g & 7) * 8;
    *reinterpret_cast<short8*>(&EnS[row][c8]) =
        *reinterpret_cast<const short8*>(
            &En[((size_t)(b * N + n0 + row)) * M + c8]);
    *reinterpret_cast<short8*>(&TpS[row][c8]) =
        *reinterpret_cast<const short8*>(
            &TpT[((size_t)(b * D + d0 + row)) * M + c8]);
  }
  __syncthreads();
  floatx4 acc[4] = {{0.f, 0.f, 0.f, 0.f},
                    {0.f, 0.f, 0.f, 0.f},
                    {0.f, 0.f, 0.f, 0.f},
                    {0.f, 0.f, 0.f, 0.f}};
  const int q8 = (l >> 4) * 8;
#pragma unroll
  for (int ks = 0; ks < 2; ++ks) {
    short8 a = *reinterpret_cast<short8*>(&EnS[w * 16 + (l & 15)][ks * 32 + q8]);
#pragma unroll
    for (int dtile = 0; dtile < 4; ++dtile) {
      short8 bf = *reinterpret_cast<short8*>(
          &TpS[dtile * 16 + (l & 15)][ks * 32 + q8]);
      acc[dtile] =
          __builtin_amdgcn_mfma_f32_16x16x32_bf16(a, bf, acc[dtile], 0, 0, 0);
    }
  }
#pragma unroll
  for (int dtile = 0; dtile < 4; ++dtile)
#pragma unroll
    for (int r = 0; r < 4; ++r) {
      const int n = n0 + w * 16 + (l >> 4) * 4 + r;
      const int d = d0 + dtile * 16 + (l & 15);
      out[((size_t)(b * N + n)) * D + d] = acc[dtile][r];
    }
}

// ---------------------------------------------------------------------------
extern "C" void kernel_launch(void* const* d_in, const int* in_sizes, int n_in,
                              void* d_out, int out_size, void* d_ws,
                              size_t ws_size, hipStream_t stream) {
  const float* x = (const float*)d_in[0];
  const float* Ws = (const float*)d_in[1];
  const float* bs = (const float*)d_in[2];
  const float* Wqkv = (const float*)d_in[3];
  const float* Wo = (const float*)d_in[4];
  const float* bo = (const float*)d_in[5];
  float* out = (float*)d_out;

  char* p = (char*)d_ws;
  unsigned short* xbT = (unsigned short*)p;      p += (size_t)B * N * D * 2;   // 33.5 MB
  unsigned short* En = (unsigned short*)p;       p += (size_t)B * N * M * 2;   // 8.4 MB
  unsigned short* Et = (unsigned short*)p;       p += (size_t)B * N * M * 2;   // 8.4 MB
  unsigned short* TpT = (unsigned short*)p;      p += (size_t)B * D * M * 2;   // 128 KB
  unsigned short* Wsb = (unsigned short*)p;      p += (size_t)M * D * 2;       // 32 KB
  float* denom = (float*)p;                      p += (size_t)B * M * 4;
  float* tokens = (float*)p;                     p += (size_t)B * M * D * 4;
  float* qkv = (float*)p;                        p += (size_t)B * M * 3 * D * 4;
  float* attn_o = (float*)p;                     p += (size_t)B * M * D * 4;

  hipMemsetAsync(denom, 0, (size_t)B * M * sizeof(float), stream);
  hipMemsetAsync(tokens, 0, (size_t)B * M * D * sizeof(float), stream);

  kws_cvt<<<dim3(16), 256, 0, stream>>>(Ws, Wsb);
  k1_fused<<<dim3(N / 32, B), 256, 0, stream>>>(x, Wsb, bs, xbT, En, Et, denom);
  k2_pool<<<dim3(D / 64, N / 512, B), 256, 0, stream>>>(Et, xbT, tokens);
  k_proj<<<dim3(12, B), 256, 0, stream>>>(tokens, Wqkv, nullptr, denom, qkv,
                                          nullptr, 768, 0);
  k4_attn<<<dim3(B * H), 256, 0, stream>>>(qkv, attn_o);
  k_proj<<<dim3(4, B), 256, 0, stream>>>(attn_o, Wo, bo, denom, nullptr, TpT,
                                         256, 1);
  k6_unpool<<<dim3(D / 64, N / 64, B), 256, 0, stream>>>(En, TpT, out);
}